// Round 1
// baseline (290.215 us; speedup 1.0000x reference)
//
#include <hip/hip_runtime.h>

// BinaryReflectanceGate: pointwise MLP (4->16->16, relu) -> segment max over
// sorted batch ids [B=64] -> 2-logit gate + gumbel softmax -> scale reflectance.
//
// Structure:
//   k0: hipMemsetAsync segmax[64][16] = 0   (relu => values >= 0, so 0 is identity)
//   k1: mlp_segmax  — 4 pts/thread, f32 MLP, wave-level max reduce, atomicMax(uint)
//   k2: gate        — 64 threads, logits + sigmoid
//   k3: scale       — out[i] = gate[batch[i]] * refl[i]

#define N_PTS 4194304
#define NB 64
#define NH 16

__global__ __launch_bounds__(256) void mlp_segmax_kernel(
    const float* __restrict__ pos,    // [N,3]
    const float* __restrict__ refl,   // [N]
    const int*   __restrict__ batch,  // [N] sorted
    const float* __restrict__ W1,     // [4,16]
    const float* __restrict__ b1,     // [16]
    const float* __restrict__ W2,     // [16,16]
    const float* __restrict__ b2,     // [16]
    unsigned int* __restrict__ segmax) // [64,16] float bits, pre-zeroed
{
    const int t  = blockIdx.x * blockDim.x + threadIdx.x;
    const int p0 = t * 4;

    const int4   bb = *reinterpret_cast<const int4*>(batch + p0);
    const float4 rr = *reinterpret_cast<const float4*>(refl + p0);
    const float4 q0 = *reinterpret_cast<const float4*>(pos + (size_t)p0 * 3);
    const float4 q1 = *reinterpret_cast<const float4*>(pos + (size_t)p0 * 3 + 4);
    const float4 q2 = *reinterpret_cast<const float4*>(pos + (size_t)p0 * 3 + 8);

    // f[p][k]: 4 input features per point (pos.xyz, reflectance)
    const float f[4][4] = {{q0.x, q0.y, q0.z, rr.x},
                           {q0.w, q1.x, q1.y, rr.y},
                           {q1.z, q1.w, q2.x, rr.z},
                           {q2.y, q2.z, q2.w, rr.w}};

    // ---- layer 1: [4]->[16], relu ----
    float h1[4][NH];
#pragma unroll
    for (int j = 0; j < NH; ++j) {
        const float bj = b1[j];
#pragma unroll
        for (int p = 0; p < 4; ++p) h1[p][j] = bj;
    }
#pragma unroll
    for (int k = 0; k < 4; ++k) {
#pragma unroll
        for (int j = 0; j < NH; ++j) {
            const float w = W1[k * NH + j];   // uniform address -> s_load
#pragma unroll
            for (int p = 0; p < 4; ++p) h1[p][j] = fmaf(f[p][k], w, h1[p][j]);
        }
    }
#pragma unroll
    for (int j = 0; j < NH; ++j)
#pragma unroll
        for (int p = 0; p < 4; ++p) h1[p][j] = fmaxf(h1[p][j], 0.f);

    // ---- layer 2: [16]->[16] ----
    float acc[4][NH];
#pragma unroll
    for (int j = 0; j < NH; ++j) {
        const float bj = b2[j];
#pragma unroll
        for (int p = 0; p < 4; ++p) acc[p][j] = bj;
    }
#pragma unroll
    for (int k = 0; k < NH; ++k) {
#pragma unroll
        for (int j = 0; j < NH; ++j) {
            const float w = W2[k * NH + j];   // uniform address -> s_load
#pragma unroll
            for (int p = 0; p < 4; ++p) acc[p][j] = fmaf(h1[p][k], w, acc[p][j]);
        }
    }

    // ---- relu + per-thread merge (batch sorted: bb.x <= bb.w) ----
    const bool straddle = (bb.x != bb.w);   // rare: ~63 threads grid-wide
    float hmax[NH];
#pragma unroll
    for (int j = 0; j < NH; ++j) {
        const float a0 = fmaxf(acc[0][j], 0.f);
        const float a1 = fmaxf(acc[1][j], 0.f);
        const float a2 = fmaxf(acc[2][j], 0.f);
        const float a3 = fmaxf(acc[3][j], 0.f);
        hmax[j] = fmaxf(fmaxf(a0, a1), fmaxf(a2, a3));
        if (straddle) {   // exec-masked off for 99.99% of waves
            atomicMax(segmax + bb.x * NH + j, __float_as_uint(a0));
            atomicMax(segmax + bb.y * NH + j, __float_as_uint(a1));
            atomicMax(segmax + bb.z * NH + j, __float_as_uint(a2));
            atomicMax(segmax + bb.w * NH + j, __float_as_uint(a3));
        }
    }
    if (straddle) {
#pragma unroll
        for (int j = 0; j < NH; ++j) hmax[j] = 0.f;  // already flushed via atomics
    }

    // ---- wave reduce: a wave spans 256 consecutive sorted points -> <=2 segments
    const int lane   = threadIdx.x & 63;
    const int bFirst = __shfl(bb.x, 0);
    const int bLast  = __shfl(bb.w, 63);

    const bool mineA = (!straddle) && (bb.x == bFirst);
#pragma unroll
    for (int j = 0; j < NH; ++j) {
        float v = mineA ? hmax[j] : 0.f;
        v = fmaxf(v, __shfl_xor(v, 1));
        v = fmaxf(v, __shfl_xor(v, 2));
        v = fmaxf(v, __shfl_xor(v, 4));
        v = fmaxf(v, __shfl_xor(v, 8));
        v = fmaxf(v, __shfl_xor(v, 16));
        v = fmaxf(v, __shfl_xor(v, 32));
        if (lane == 0) atomicMax(segmax + bFirst * NH + j, __float_as_uint(v));
    }
    if (bLast != bFirst) {   // wave-uniform branch
        const bool mineB = (!straddle) && (bb.x == bLast);
#pragma unroll
        for (int j = 0; j < NH; ++j) {
            float v = mineB ? hmax[j] : 0.f;
            v = fmaxf(v, __shfl_xor(v, 1));
            v = fmaxf(v, __shfl_xor(v, 2));
            v = fmaxf(v, __shfl_xor(v, 4));
            v = fmaxf(v, __shfl_xor(v, 8));
            v = fmaxf(v, __shfl_xor(v, 16));
            v = fmaxf(v, __shfl_xor(v, 32));
            if (lane == 0) atomicMax(segmax + bLast * NH + j, __float_as_uint(v));
        }
    }
}

__global__ void gate_kernel(const unsigned int* __restrict__ segmax, // [64,16]
                            const float* __restrict__ Wg,            // [16,2]
                            const float* __restrict__ bg,            // [2]
                            const float* __restrict__ gumbels,       // [64,2]
                            float* __restrict__ gate)                // [64]
{
    const int b = threadIdx.x;
    float l0 = bg[0] + gumbels[b * 2 + 0];
    float l1 = bg[1] + gumbels[b * 2 + 1];
#pragma unroll
    for (int d = 0; d < NH; ++d) {
        const float s = __uint_as_float(segmax[b * NH + d]);
        l0 = fmaf(s, Wg[d * 2 + 0], l0);
        l1 = fmaf(s, Wg[d * 2 + 1], l1);
    }
    const float z = l1 - l0;            // TAU = 1.0
    gate[b] = 1.f / (1.f + expf(-z));   // softmax[:,1] == sigmoid(l1-l0)
}

__global__ __launch_bounds__(256) void scale_kernel(
    const float* __restrict__ refl,
    const int*   __restrict__ batch,
    const float* __restrict__ gate,
    float* __restrict__ out)
{
    __shared__ float g[NB];
    if (threadIdx.x < NB) g[threadIdx.x] = gate[threadIdx.x];
    __syncthreads();

    const int t  = blockIdx.x * blockDim.x + threadIdx.x;
    const int p0 = t * 4;
    const int4   bb = *reinterpret_cast<const int4*>(batch + p0);
    const float4 rr = *reinterpret_cast<const float4*>(refl + p0);
    float4 o;
    o.x = g[bb.x] * rr.x;
    o.y = g[bb.y] * rr.y;
    o.z = g[bb.z] * rr.z;
    o.w = g[bb.w] * rr.w;
    *reinterpret_cast<float4*>(out + p0) = o;
}

extern "C" void kernel_launch(void* const* d_in, const int* in_sizes, int n_in,
                              void* d_out, int out_size, void* d_ws, size_t ws_size,
                              hipStream_t stream) {
    const float* pos   = (const float*)d_in[0];
    const float* refl  = (const float*)d_in[1];
    const int*   batch = (const int*)d_in[2];
    const float* gumb  = (const float*)d_in[3];
    const float* W1    = (const float*)d_in[4];
    const float* b1    = (const float*)d_in[5];
    const float* W2    = (const float*)d_in[6];
    const float* b2    = (const float*)d_in[7];
    const float* Wg    = (const float*)d_in[8];
    const float* bg    = (const float*)d_in[9];
    float* out = (float*)d_out;

    unsigned int* segmax = (unsigned int*)d_ws;                 // 64*16*4 = 4 KB
    float*        gate   = (float*)((char*)d_ws + 4096);        // 64 floats

    hipMemsetAsync(segmax, 0, NB * NH * sizeof(unsigned int), stream);

    const int threads = N_PTS / 4;          // 4 points per thread
    mlp_segmax_kernel<<<threads / 256, 256, 0, stream>>>(pos, refl, batch,
                                                         W1, b1, W2, b2, segmax);
    gate_kernel<<<1, NB, 0, stream>>>(segmax, Wg, bg, gumb, gate);
    scale_kernel<<<threads / 256, 256, 0, stream>>>(refl, batch, gate, out);
}

// Round 3
// 83.716 us; speedup vs baseline: 3.4667x; 3.4667x over previous
//
#include <hip/hip_runtime.h>

// BinaryReflectanceGate: pointwise MLP (4->16->16, relu) -> segment max over
// sorted batch ids [B=64] -> 2-logit gate + gumbel softmax -> scale reflectance.
//
// Round-3 structure (atomic-free segmax; r2 + compile fix):
//   memset: fallback[64][16] = 0 (straddle-thread atomics only, ~4K total)
//   prep:   pack/transpose weights into ws (contiguous rows -> s_load streams)
//   main:   4 pts/thread, 1024-thr blocks; f32 MLP; 15-shfl dimension-splitting
//           wave butterfly; LDS block combine; block WRITES its <=2 segment
//           partials (no global atomics on the hot path)
//   stage2: 1 block reduces 1024 block-partials + fallback -> segmax -> gate
//   scale:  out[i] = gate[batch[i]] * refl[i]

#define N_PTS 4194304
#define NB 64
#define NH 16
#define BLK 1024                 // threads per main block
#define PPT 4                    // points per thread
#define NBLK (N_PTS / (BLK * PPT))   // 1024 main blocks
#define NW (BLK / 64)            // 16 waves per block

// ---------------- weight prep: pack + transpose into ws ----------------
// wp[j*8 + k]        = W1[k][j]  (k<4), wp[j*8+4] = b1[j]          (rows 32B)
// wp[128 + j*24 + k] = W2[k][j]  (k<16), wp[128+j*24+16] = b2[j]   (rows 96B)
__global__ void prep_kernel(const float* __restrict__ W1, const float* __restrict__ b1,
                            const float* __restrict__ W2, const float* __restrict__ b2,
                            float* __restrict__ wp) {
    const int j = threadIdx.x;
    if (j < NH) {
#pragma unroll
        for (int k = 0; k < 4; ++k) wp[j * 8 + k] = W1[k * NH + j];
        wp[j * 8 + 4] = b1[j];
        const int base = 128 + j * 24;
#pragma unroll
        for (int k = 0; k < NH; ++k) wp[base + k] = W2[k * NH + j];
        wp[base + 16] = b2[j];
    }
}

// ---------------- wave butterfly: reduce hv[16] across 64 lanes ----------------
// Returns, in every lane, the wave max of dim d(lane) = bitrev4(lane&15).
__device__ __forceinline__ float butterfly16(const float hv[16], int lane) {
    float a[8];
    const bool k0 = (lane & 1) == 0;
#pragma unroll
    for (int i = 0; i < 8; ++i) {
        const float kp = k0 ? hv[i] : hv[i + 8];
        const float sd = k0 ? hv[i + 8] : hv[i];
        a[i] = fmaxf(kp, __shfl_xor(sd, 1));
    }
    float b[4];
    const bool k1 = (lane & 2) == 0;
#pragma unroll
    for (int i = 0; i < 4; ++i) {
        const float kp = k1 ? a[i] : a[i + 4];
        const float sd = k1 ? a[i + 4] : a[i];
        b[i] = fmaxf(kp, __shfl_xor(sd, 2));
    }
    float c[2];
    const bool k2 = (lane & 4) == 0;
#pragma unroll
    for (int i = 0; i < 2; ++i) {
        const float kp = k2 ? b[i] : b[i + 2];
        const float sd = k2 ? b[i + 2] : b[i];
        c[i] = fmaxf(kp, __shfl_xor(sd, 4));
    }
    const bool k3 = (lane & 8) == 0;
    const float kp = k3 ? c[0] : c[1];
    const float sd = k3 ? c[1] : c[0];
    float d = fmaxf(kp, __shfl_xor(sd, 8));
    d = fmaxf(d, __shfl_xor(d, 16));
    d = fmaxf(d, __shfl_xor(d, 32));
    return d;
}

// ---------------- main: MLP + segment max partials ----------------
__global__ __launch_bounds__(BLK, 4) void mlp_segmax_kernel(
    const float* __restrict__ pos,    // [N,3]
    const float* __restrict__ refl,   // [N]
    const int*   __restrict__ batch,  // [N] sorted
    const float* __restrict__ wp,     // packed weights (see prep)
    unsigned int* __restrict__ fb,    // [64,16] fallback (pre-zeroed)
    float* __restrict__ pv,           // [NBLK,2,16] partial vals
    int*   __restrict__ pid)          // [NBLK,2]   partial ids
{
    __shared__ float lv[NW][2][NH];
    __shared__ int   li[NW][2];

    const int t  = blockIdx.x * BLK + threadIdx.x;
    const int p0 = t * PPT;
    const int lane = threadIdx.x & 63;
    const int wid  = threadIdx.x >> 6;

    const int4   bb = *reinterpret_cast<const int4*>(batch + p0);
    const float4 rr = *reinterpret_cast<const float4*>(refl + p0);
    const float4 q0 = *reinterpret_cast<const float4*>(pos + (size_t)p0 * 3);
    const float4 q1 = *reinterpret_cast<const float4*>(pos + (size_t)p0 * 3 + 4);
    const float4 q2 = *reinterpret_cast<const float4*>(pos + (size_t)p0 * 3 + 8);

    const float f[4][4] = {{q0.x, q0.y, q0.z, rr.x},
                           {q0.w, q1.x, q1.y, rr.y},
                           {q1.z, q1.w, q2.x, rr.z},
                           {q2.y, q2.z, q2.w, rr.w}};

    // ---- layer 1: [4]->[16], relu (weights via contiguous s_load rows) ----
    float h[PPT][NH];
#pragma unroll
    for (int j = 0; j < NH; ++j) {
        const float4 w  = *reinterpret_cast<const float4*>(wp + j * 8);
        const float  bj = wp[j * 8 + 4];
#pragma unroll
        for (int p = 0; p < PPT; ++p) {
            float acc = bj;
            acc = fmaf(f[p][0], w.x, acc);
            acc = fmaf(f[p][1], w.y, acc);
            acc = fmaf(f[p][2], w.z, acc);
            acc = fmaf(f[p][3], w.w, acc);
            h[p][j] = fmaxf(acc, 0.f);
        }
    }

    // ---- layer 2: [16]->[16], streamed per output dim j ----
    const bool straddle = (bb.x != bb.w);   // ~63 threads grid-wide
    float hm[NH];
#pragma unroll
    for (int j = 0; j < NH; ++j) {
        const float* r2 = wp + 128 + j * 24;
        const float4 wa = *reinterpret_cast<const float4*>(r2);
        const float4 wb = *reinterpret_cast<const float4*>(r2 + 4);
        const float4 wc = *reinterpret_cast<const float4*>(r2 + 8);
        const float4 wd = *reinterpret_cast<const float4*>(r2 + 12);
        const float  bj = r2[16];
        float a[PPT];
#pragma unroll
        for (int p = 0; p < PPT; ++p) {
            float acc = bj;
            acc = fmaf(h[p][0],  wa.x, acc);
            acc = fmaf(h[p][1],  wa.y, acc);
            acc = fmaf(h[p][2],  wa.z, acc);
            acc = fmaf(h[p][3],  wa.w, acc);
            acc = fmaf(h[p][4],  wb.x, acc);
            acc = fmaf(h[p][5],  wb.y, acc);
            acc = fmaf(h[p][6],  wb.z, acc);
            acc = fmaf(h[p][7],  wb.w, acc);
            acc = fmaf(h[p][8],  wc.x, acc);
            acc = fmaf(h[p][9],  wc.y, acc);
            acc = fmaf(h[p][10], wc.z, acc);
            acc = fmaf(h[p][11], wc.w, acc);
            acc = fmaf(h[p][12], wd.x, acc);
            acc = fmaf(h[p][13], wd.y, acc);
            acc = fmaf(h[p][14], wd.z, acc);
            acc = fmaf(h[p][15], wd.w, acc);
            a[p] = acc;
        }
        if (straddle) {   // rare divergent path: flush per-point via atomics
            atomicMax(fb + bb.x * NH + j, __float_as_uint(fmaxf(a[0], 0.f)));
            atomicMax(fb + bb.y * NH + j, __float_as_uint(fmaxf(a[1], 0.f)));
            atomicMax(fb + bb.z * NH + j, __float_as_uint(fmaxf(a[2], 0.f)));
            atomicMax(fb + bb.w * NH + j, __float_as_uint(fmaxf(a[3], 0.f)));
            hm[j] = 0.f;
        } else {
            hm[j] = fmaxf(fmaxf(fmaxf(a[0], a[1]), fmaxf(a[2], a[3])), 0.f);
        }
    }

    // ---- wave reduce (<=2 segments per 256-pt wave) ----
    const int bFirst = __shfl(bb.x, 0);
    const int bLast  = __shfl(bb.w, 63);
    const int dmap = ((lane & 1) << 3) | ((lane & 2) << 1) |
                     ((lane & 4) >> 1) | ((lane & 8) >> 3);

    {
        float v[NH];
        const bool mineA = (bb.x == bFirst);
#pragma unroll
        for (int i = 0; i < NH; ++i) v[i] = mineA ? hm[i] : 0.f;
        const float r = butterfly16(v, lane);
        if (lane < 16) lv[wid][0][dmap] = r;
        if (lane == 0) li[wid][0] = bFirst;
    }
    if (bFirst != bLast) {       // wave-uniform, rare (boundary waves)
        float v[NH];
        const bool mineB = (bb.x == bLast);
#pragma unroll
        for (int i = 0; i < NH; ++i) v[i] = mineB ? hm[i] : 0.f;
        const float r = butterfly16(v, lane);
        if (lane < 16) lv[wid][1][dmap] = r;
        if (lane == 0) li[wid][1] = bLast;
    } else {
        if (lane < 16) lv[wid][1][lane] = 0.f;
        if (lane == 0) li[wid][1] = bFirst;
    }
    __syncthreads();

    // ---- block combine: block spans <=2 segments; write partials ----
    if (threadIdx.x < NH) {
        const int d   = threadIdx.x;
        const int idA = li[0][0];
        const int idB = li[NW - 1][1];
        float mA = 0.f, mB = 0.f;
#pragma unroll
        for (int s = 0; s < NW; ++s) {
#pragma unroll
            for (int hh = 0; hh < 2; ++hh) {
                const float val = lv[s][hh][d];
                if (li[s][hh] == idA) mA = fmaxf(mA, val);
                else                  mB = fmaxf(mB, val);
            }
        }
        pv[(blockIdx.x * 2 + 0) * NH + d] = mA;
        pv[(blockIdx.x * 2 + 1) * NH + d] = mB;
        if (d == 0) {
            pid[blockIdx.x * 2 + 0] = idA;
            pid[blockIdx.x * 2 + 1] = idB;
        }
    }
}

// ---------------- stage 2: combine partials, compute gate ----------------
__global__ __launch_bounds__(1024) void stage2_kernel(
    const float* __restrict__ pv, const int* __restrict__ pid,
    const unsigned int* __restrict__ fb,
    const float* __restrict__ Wg, const float* __restrict__ bg,
    const float* __restrict__ gum, float* __restrict__ gate)
{
    __shared__ unsigned int sm[NB * NH];   // 64 x 16
    const int tid = threadIdx.x;
    sm[tid] = 0u;
    __syncthreads();

    const int d = tid & 15;
    const int c = tid >> 4;                // 0..63
    for (int b = c; b < NBLK; b += 64) {
#pragma unroll
        for (int hh = 0; hh < 2; ++hh) {
            const int   id = pid[b * 2 + hh];
            const float v  = pv[(b * 2 + hh) * NH + d];
            atomicMax(&sm[id * NH + d], __float_as_uint(v));
        }
    }
    __syncthreads();
    {   // merge straddle fallback
        const unsigned int a = sm[tid], b2 = fb[tid];
        sm[tid] = a > b2 ? a : b2;
    }
    __syncthreads();

    if (tid < NB) {
        float l0 = bg[0] + gum[tid * 2 + 0];
        float l1 = bg[1] + gum[tid * 2 + 1];
#pragma unroll
        for (int k = 0; k < NH; ++k) {
            const float s = __uint_as_float(sm[tid * NH + k]);
            l0 = fmaf(s, Wg[k * 2 + 0], l0);
            l1 = fmaf(s, Wg[k * 2 + 1], l1);
        }
        gate[tid] = 1.f / (1.f + expf(-(l1 - l0)));
    }
}

// ---------------- scale ----------------
__global__ __launch_bounds__(256) void scale_kernel(
    const float* __restrict__ refl,
    const int*   __restrict__ batch,
    const float* __restrict__ gate,
    float* __restrict__ out)
{
    __shared__ float g[NB];
    if (threadIdx.x < NB) g[threadIdx.x] = gate[threadIdx.x];
    __syncthreads();

    const int t  = blockIdx.x * blockDim.x + threadIdx.x;
    const int p0 = t * 4;
    const int4   bb = *reinterpret_cast<const int4*>(batch + p0);
    const float4 rr = *reinterpret_cast<const float4*>(refl + p0);
    float4 o;
    o.x = g[bb.x] * rr.x;
    o.y = g[bb.y] * rr.y;
    o.z = g[bb.z] * rr.z;
    o.w = g[bb.w] * rr.w;
    *reinterpret_cast<float4*>(out + p0) = o;
}

extern "C" void kernel_launch(void* const* d_in, const int* in_sizes, int n_in,
                              void* d_out, int out_size, void* d_ws, size_t ws_size,
                              hipStream_t stream) {
    const float* pos   = (const float*)d_in[0];
    const float* refl  = (const float*)d_in[1];
    const int*   batch = (const int*)d_in[2];
    const float* gumb  = (const float*)d_in[3];
    const float* W1    = (const float*)d_in[4];
    const float* b1    = (const float*)d_in[5];
    const float* W2    = (const float*)d_in[6];
    const float* b2    = (const float*)d_in[7];
    const float* Wg    = (const float*)d_in[8];
    const float* bg    = (const float*)d_in[9];
    float* out = (float*)d_out;

    // ws layout
    unsigned int* fb    = (unsigned int*)d_ws;                       // 4 KB
    float*        gate  = (float*)((char*)d_ws + 4096);              // 256 B
    float*        wp    = (float*)((char*)d_ws + 8192);              // 2 KB
    float*        pv    = (float*)((char*)d_ws + 16384);             // 128 KB
    int*          pid   = (int*)((char*)d_ws + 16384 + NBLK * 2 * NH * sizeof(float));

    (void)hipMemsetAsync(fb, 0, NB * NH * sizeof(unsigned int), stream);
    prep_kernel<<<1, 64, 0, stream>>>(W1, b1, W2, b2, wp);
    mlp_segmax_kernel<<<NBLK, BLK, 0, stream>>>(pos, refl, batch, wp, fb, pv, pid);
    stage2_kernel<<<1, 1024, 0, stream>>>(pv, pid, fb, Wg, bg, gumb, gate);
    scale_kernel<<<N_PTS / 4 / 256, 256, 0, stream>>>(refl, batch, gate, out);
}

// Round 4
// 53.756 us; speedup vs baseline: 5.3987x; 1.5573x over previous
//
#include <hip/hip_runtime.h>

// BinaryReflectanceGate: pointwise MLP (4->16->16, relu) -> segment max over
// sorted batch ids [B=64] -> 2-logit gate + gumbel softmax -> scale reflectance.
//
// Round-4: MFMA MLP. Key layout facts:
//  - mfma_f32_16x16x32_bf16 C/D: col=lane&15, row=(lane>>4)*4+reg (HW-verified).
//  - A/B k-slots: ANY consistent (lane,elem)->k assignment works (contraction is
//    invariant under k-permutation as long as A and B use the same map).
//  - Layer 1: features of point base+lane sit in lane-group g=lane>>4; tile t's
//    B zeroes all groups != t, and A1 replicates W1 across all k-groups
//    => no cross-lane movement for inputs.
//  - Layer 2: D-fragment (dims 4g..4g+3 per lane) IS the B2 fragment slot
//    {P0,P1,0,0} under map k=4g+e => chaining is the identity. A2[e]=W2[4g+e][col].
//  - batch[] read only twice per wave (sorted; wave=512 pts spans <=2 segments,
//    min segment ~64.8K). Straddle waves (~63/4096) take a select-based slow path.

#define N_PTS 4194304
#define NB 64
#define NH 16
#define WPB 4                      // waves per block
#define PTW 512                    // points per wave
#define PPB (WPB * PTW)            // 2048 points per block
#define NBLK_MAIN (N_PTS / PPB)    // 2048 blocks
#define ITERS (PTW / 64)           // 8

typedef __attribute__((ext_vector_type(8))) short bf16x8;
typedef __attribute__((ext_vector_type(4))) float f32x4;

union U8 { bf16x8 v; unsigned u[4]; unsigned short s[8]; };

__device__ __forceinline__ unsigned short f2bf(float x) {   // RNE f32->bf16
    unsigned u = __float_as_uint(x);
    u = u + 0x7fffu + ((u >> 16) & 1u);
    return (unsigned short)(u >> 16);
}
__device__ __forceinline__ unsigned pk2(float a, float b) {
    return (unsigned)f2bf(a) | ((unsigned)f2bf(b) << 16);
}

__global__ __launch_bounds__(256) void mlp_segmax_kernel(
    const float* __restrict__ pos,    // [N,3]
    const float* __restrict__ refl,   // [N]
    const int*   __restrict__ batch,  // [N] sorted
    const float* __restrict__ W1,     // [4,16]
    const float* __restrict__ b1,     // [16]
    const float* __restrict__ W2,     // [16,16]
    const float* __restrict__ b2,     // [16]
    float* __restrict__ pv,           // [NBLK_MAIN,2,16]
    int*   __restrict__ pid)          // [NBLK_MAIN,2]
{
    __shared__ float lv[WPB][2][NH];
    __shared__ int   li[WPB][2];

    const int lane = threadIdx.x & 63;
    const int wid  = threadIdx.x >> 6;
    const int col  = lane & 15;
    const int g    = lane >> 4;
    const int wb   = (blockIdx.x * WPB + wid) * PTW;

    // ---- weight / bias fragments (one-time, L1-cached loads) ----
    U8 A1, A2;
#pragma unroll
    for (int e = 0; e < 4; ++e) {
        A1.s[e]     = f2bf(W1[e * NH + col]);           // replicated over g
        A1.s[e + 4] = 0;
        A2.s[e]     = f2bf(W2[(4 * g + e) * NH + col]); // k = 4g+e
        A2.s[e + 4] = 0;
    }
    f32x4 c1, c2;
#pragma unroll
    for (int r = 0; r < 4; ++r) { c1[r] = b1[4 * g + r]; c2[r] = b2[4 * g + r]; }

    const int idA = batch[wb];
    const int idB = batch[wb + PTW - 1];

    f32x4 accA = {0.f, 0.f, 0.f, 0.f};
    f32x4 accB = {0.f, 0.f, 0.f, 0.f};

    if (idA == idB) {
        // ---- fast path: whole wave in one segment; no batch loads ----
        for (int it = 0; it < ITERS; ++it) {
            const int idx = wb + it * 64 + lane;
            const float x = pos[idx * 3 + 0];
            const float y = pos[idx * 3 + 1];
            const float z = pos[idx * 3 + 2];
            const float w = refl[idx];
            const unsigned F01 = pk2(x, y), F23 = pk2(z, w);
#pragma unroll
            for (int t = 0; t < 4; ++t) {
                const bool mine = (g == t);
                U8 B;
                B.u[0] = mine ? F01 : 0u;
                B.u[1] = mine ? F23 : 0u;
                B.u[2] = 0u; B.u[3] = 0u;
                f32x4 d = __builtin_amdgcn_mfma_f32_16x16x32_bf16(A1.v, B.v, c1, 0, 0, 0);
                U8 P;
                P.u[0] = pk2(fmaxf(d[0], 0.f), fmaxf(d[1], 0.f));
                P.u[1] = pk2(fmaxf(d[2], 0.f), fmaxf(d[3], 0.f));
                P.u[2] = 0u; P.u[3] = 0u;
                f32x4 h = __builtin_amdgcn_mfma_f32_16x16x32_bf16(A2.v, P.v, c2, 0, 0, 0);
#pragma unroll
                for (int r = 0; r < 4; ++r) accA[r] = fmaxf(accA[r], h[r]); // relu via acc>=0
            }
        }
    } else {
        // ---- slow path (~63 waves): per-tile ids, select into accA/accB ----
        for (int it = 0; it < ITERS; ++it) {
            const int base = wb + it * 64;
            const int idx  = base + lane;
            const float x = pos[idx * 3 + 0];
            const float y = pos[idx * 3 + 1];
            const float z = pos[idx * 3 + 2];
            const float w = refl[idx];
            const unsigned F01 = pk2(x, y), F23 = pk2(z, w);
#pragma unroll
            for (int t = 0; t < 4; ++t) {
                const bool mine = (g == t);
                U8 B;
                B.u[0] = mine ? F01 : 0u;
                B.u[1] = mine ? F23 : 0u;
                B.u[2] = 0u; B.u[3] = 0u;
                f32x4 d = __builtin_amdgcn_mfma_f32_16x16x32_bf16(A1.v, B.v, c1, 0, 0, 0);
                U8 P;
                P.u[0] = pk2(fmaxf(d[0], 0.f), fmaxf(d[1], 0.f));
                P.u[1] = pk2(fmaxf(d[2], 0.f), fmaxf(d[3], 0.f));
                P.u[2] = 0u; P.u[3] = 0u;
                f32x4 h = __builtin_amdgcn_mfma_f32_16x16x32_bf16(A2.v, P.v, c2, 0, 0, 0);
                const int  pt_id = batch[base + t * 16 + col];  // id of this D-column
                const bool m = (pt_id == idA);
#pragma unroll
                for (int r = 0; r < 4; ++r) {
                    accA[r] = fmaxf(accA[r], m ? h[r] : 0.f);
                    accB[r] = fmaxf(accB[r], m ? 0.f : h[r]);
                }
            }
        }
    }

    // ---- reduce over 16 columns (lanes sharing a k-group) ----
#pragma unroll
    for (int mk = 1; mk <= 8; mk <<= 1) {
#pragma unroll
        for (int r = 0; r < 4; ++r) {
            accA[r] = fmaxf(accA[r], __shfl_xor(accA[r], mk));
            accB[r] = fmaxf(accB[r], __shfl_xor(accB[r], mk));
        }
    }
    if (col == 0) {   // lanes 0,16,32,48 hold dims 4g..4g+3
        *reinterpret_cast<float4*>(&lv[wid][0][4 * g]) =
            make_float4(accA[0], accA[1], accA[2], accA[3]);
        *reinterpret_cast<float4*>(&lv[wid][1][4 * g]) =
            make_float4(accB[0], accB[1], accB[2], accB[3]);
    }
    if (lane == 0) { li[wid][0] = idA; li[wid][1] = idB; }
    __syncthreads();

    // ---- block combine: block spans <=2 segments; write partials ----
    if (threadIdx.x < NH) {
        const int d   = threadIdx.x;
        const int ida = li[0][0];
        const int idb = li[WPB - 1][1];
        float mA = 0.f, mB = 0.f;
#pragma unroll
        for (int s = 0; s < WPB; ++s)
#pragma unroll
            for (int hh = 0; hh < 2; ++hh) {
                const float val = lv[s][hh][d];
                if (li[s][hh] == ida) mA = fmaxf(mA, val);
                else                  mB = fmaxf(mB, val);
            }
        pv[(blockIdx.x * 2 + 0) * NH + d] = mA;
        pv[(blockIdx.x * 2 + 1) * NH + d] = mB;
        if (d == 0) {
            pid[blockIdx.x * 2 + 0] = ida;
            pid[blockIdx.x * 2 + 1] = idb;
        }
    }
}

// ---------------- stage 2: combine partials, compute gate ----------------
__global__ __launch_bounds__(1024) void stage2_kernel(
    const float* __restrict__ pv, const int* __restrict__ pid,
    const float* __restrict__ Wg, const float* __restrict__ bg,
    const float* __restrict__ gum, float* __restrict__ gate)
{
    __shared__ unsigned int sm[NB * NH];   // 64 x 16, float bits (vals >= 0)
    const int tid = threadIdx.x;
    sm[tid] = 0u;
    __syncthreads();

    const int d = tid & 15;
    const int c = tid >> 4;                // 0..63
    for (int b = c; b < NBLK_MAIN; b += 64) {
#pragma unroll
        for (int hh = 0; hh < 2; ++hh) {
            const int   id = pid[b * 2 + hh];
            const float v  = pv[(b * 2 + hh) * NH + d];
            atomicMax(&sm[id * NH + d], __float_as_uint(v));
        }
    }
    __syncthreads();

    if (tid < NB) {
        float l0 = bg[0] + gum[tid * 2 + 0];
        float l1 = bg[1] + gum[tid * 2 + 1];
#pragma unroll
        for (int k = 0; k < NH; ++k) {
            const float s = __uint_as_float(sm[tid * NH + k]);
            l0 = fmaf(s, Wg[k * 2 + 0], l0);
            l1 = fmaf(s, Wg[k * 2 + 1], l1);
        }
        gate[tid] = 1.f / (1.f + expf(-(l1 - l0)));   // softmax[:,1], TAU=1
    }
}

// ---------------- scale ----------------
__global__ __launch_bounds__(256) void scale_kernel(
    const float* __restrict__ refl,
    const int*   __restrict__ batch,
    const float* __restrict__ gate,
    float* __restrict__ out)
{
    __shared__ float g[NB];
    if (threadIdx.x < NB) g[threadIdx.x] = gate[threadIdx.x];
    __syncthreads();

    const int t  = blockIdx.x * blockDim.x + threadIdx.x;
    const int p0 = t * 4;
    const int4   bb = *reinterpret_cast<const int4*>(batch + p0);
    const float4 rr = *reinterpret_cast<const float4*>(refl + p0);
    float4 o;
    o.x = g[bb.x] * rr.x;
    o.y = g[bb.y] * rr.y;
    o.z = g[bb.z] * rr.z;
    o.w = g[bb.w] * rr.w;
    *reinterpret_cast<float4*>(out + p0) = o;
}

extern "C" void kernel_launch(void* const* d_in, const int* in_sizes, int n_in,
                              void* d_out, int out_size, void* d_ws, size_t ws_size,
                              hipStream_t stream) {
    const float* pos   = (const float*)d_in[0];
    const float* refl  = (const float*)d_in[1];
    const int*   batch = (const int*)d_in[2];
    const float* gumb  = (const float*)d_in[3];
    const float* W1    = (const float*)d_in[4];
    const float* b1    = (const float*)d_in[5];
    const float* W2    = (const float*)d_in[6];
    const float* b2    = (const float*)d_in[7];
    const float* Wg    = (const float*)d_in[8];
    const float* bg    = (const float*)d_in[9];
    float* out = (float*)d_out;

    // ws layout: pv 256KB | pid 16KB | gate
    float* pv   = (float*)d_ws;
    int*   pid  = (int*)((char*)d_ws + NBLK_MAIN * 2 * NH * sizeof(float));
    float* gate = (float*)((char*)d_ws + NBLK_MAIN * 2 * NH * sizeof(float)
                                       + NBLK_MAIN * 2 * sizeof(int));

    mlp_segmax_kernel<<<NBLK_MAIN, 256, 0, stream>>>(pos, refl, batch,
                                                     W1, b1, W2, b2, pv, pid);
    stage2_kernel<<<1, 1024, 0, stream>>>(pv, pid, Wg, bg, gumb, gate);
    scale_kernel<<<N_PTS / 4 / 256, 256, 0, stream>>>(refl, batch, gate, out);
}

// Round 6
// 42.888 us; speedup vs baseline: 6.7668x; 1.2534x over previous
//
#include <hip/hip_runtime.h>
#include <hip/hip_bf16.h>

// BinaryReflectanceGate: pointwise MLP (4->16->16, relu) -> segment max over
// sorted batch ids [B=64] -> 2-logit gate + gumbel softmax -> scale reflectance.
//
// Round-6 (r5 + compile fix: memcpy instead of bit_cast for __hip_bfloat162):
//   A: mlp_segmax — MFMA MLP (proven r4 layout), 1024 blk x 4 waves x 1024 pts.
//      bf16 pack via __float22bfloat162_rn; straddle waves resolve the segment
//      boundary POSITION once, then select by compare (no batch loads in loop).
//      Writes per-block partials (pv/pid) + records {idA,idB,bpos}.
//   stage2: 1 block/1024 thr reduces 2048 partial entries -> segmax -> gate[64].
//   B: scale — reads records (not batch!): out = gate[id(p)] * refl. 32 MB.
//
// MFMA layout facts (HW-verified r4, absmax 0.0039):
//   C/D: col=lane&15, row=(lane>>4)*4+reg. A lane(g,c) holds A[row=c][k=4g+e];
//   B lane(g,c) holds B[k=4g+e][col=c]. Point at lane l feeds column c=l&15 at
//   k-group g=l>>4 (identity placement); layer-1 D fragment IS the layer-2 B
//   fragment under the same k-map.

#define N_PTS 4194304
#define NB 64
#define NH 16
#define WPB 4                       // waves per block
#define ITERS 16                    // 64-pt iterations per wave
#define PTW (64 * ITERS)            // 1024 points per wave
#define PPB (WPB * PTW)             // 4096 points per block
#define NBLK (N_PTS / PPB)          // 1024 blocks
#define NENT (NBLK * 2)             // 2048 partial entries

typedef __attribute__((ext_vector_type(8))) short bf16x8;
typedef __attribute__((ext_vector_type(4))) float f32x4;
union U8 { bf16x8 v; unsigned u[4]; unsigned short s[8]; };

struct Rec { int idA, idB, bpos; };

__device__ __forceinline__ unsigned pk2(float a, float b) {
    float2 t; t.x = a; t.y = b;
    __hip_bfloat162 r = __float22bfloat162_rn(t);
    unsigned u;
    __builtin_memcpy(&u, &r, sizeof(u));
    return u;
}
__device__ __forceinline__ unsigned short f2bf(float x) {   // RNE, weight setup only
    unsigned u = __float_as_uint(x);
    u = u + 0x7fffu + ((u >> 16) & 1u);
    return (unsigned short)(u >> 16);
}

// ---------------- A: MLP + segment-max partials + records ----------------
__global__ __launch_bounds__(256) void mlp_segmax_kernel(
    const float* __restrict__ pos,    // [N,3]
    const float* __restrict__ refl,   // [N]
    const int*   __restrict__ batch,  // [N] sorted
    const float* __restrict__ W1, const float* __restrict__ b1,
    const float* __restrict__ W2, const float* __restrict__ b2,
    float* __restrict__ pv,           // [NENT,16]
    int*   __restrict__ pid,          // [NENT]
    Rec*   __restrict__ recs)         // [NBLK]
{
    __shared__ float lv[WPB][2][NH];
    __shared__ int   li[WPB][2];
    __shared__ int   lbp[WPB];

    const int lane = threadIdx.x & 63;
    const int wid  = threadIdx.x >> 6;
    const int col  = lane & 15;
    const int g    = lane >> 4;
    const int wb   = (blockIdx.x * WPB + wid) * PTW;

    // weight / bias fragments (L1-cached one-time loads)
    U8 A1, A2;
#pragma unroll
    for (int e = 0; e < 4; ++e) {
        A1.s[e]     = f2bf(W1[e * NH + col]);
        A1.s[e + 4] = 0;
        A2.s[e]     = f2bf(W2[(4 * g + e) * NH + col]);
        A2.s[e + 4] = 0;
    }
    f32x4 c1, c2;
#pragma unroll
    for (int r = 0; r < 4; ++r) { c1[r] = b1[4 * g + r]; c2[r] = b2[4 * g + r]; }

    const int idA = batch[wb];
    const int idB = batch[wb + PTW - 1];

    f32x4 accA = {0.f, 0.f, 0.f, 0.f};
    f32x4 accB = {0.f, 0.f, 0.f, 0.f};
    int bposw = 0x7fffffff;

    if (idA == idB) {
        // ---- fast path: wave entirely inside one segment ----
#pragma unroll 2
        for (int it = 0; it < ITERS; ++it) {
            const int idx = wb + it * 64 + lane;
            const float x = pos[idx * 3 + 0];
            const float y = pos[idx * 3 + 1];
            const float z = pos[idx * 3 + 2];
            const float w = refl[idx];
            const unsigned F01 = pk2(x, y), F23 = pk2(z, w);
#pragma unroll
            for (int t = 0; t < 4; ++t) {
                const bool mine = (g == t);
                U8 B;
                B.u[0] = mine ? F01 : 0u;
                B.u[1] = mine ? F23 : 0u;
                B.u[2] = 0u; B.u[3] = 0u;
                f32x4 d = __builtin_amdgcn_mfma_f32_16x16x32_bf16(A1.v, B.v, c1, 0, 0, 0);
                U8 P;
                P.u[0] = pk2(fmaxf(d[0], 0.f), fmaxf(d[1], 0.f));
                P.u[1] = pk2(fmaxf(d[2], 0.f), fmaxf(d[3], 0.f));
                P.u[2] = 0u; P.u[3] = 0u;
                f32x4 h = __builtin_amdgcn_mfma_f32_16x16x32_bf16(A2.v, P.v, c2, 0, 0, 0);
#pragma unroll
                for (int r = 0; r < 4; ++r) accA[r] = fmaxf(accA[r], h[r]);
            }
        }
    } else {
        // ---- slow path (~63 waves): locate boundary, then select by compare
        for (int it = 0; it < ITERS; ++it) {
            const int idx = wb + it * 64 + lane;
            const unsigned long long mk = __ballot(batch[idx] != idA);
            if (mk) bposw = min(bposw, wb + it * 64 + (__ffsll((long long)mk) - 1));
        }
#pragma unroll 2
        for (int it = 0; it < ITERS; ++it) {
            const int base = wb + it * 64;
            const int idx  = base + lane;
            const float x = pos[idx * 3 + 0];
            const float y = pos[idx * 3 + 1];
            const float z = pos[idx * 3 + 2];
            const float w = refl[idx];
            const unsigned F01 = pk2(x, y), F23 = pk2(z, w);
#pragma unroll
            for (int t = 0; t < 4; ++t) {
                const bool mine = (g == t);
                U8 B;
                B.u[0] = mine ? F01 : 0u;
                B.u[1] = mine ? F23 : 0u;
                B.u[2] = 0u; B.u[3] = 0u;
                f32x4 d = __builtin_amdgcn_mfma_f32_16x16x32_bf16(A1.v, B.v, c1, 0, 0, 0);
                U8 P;
                P.u[0] = pk2(fmaxf(d[0], 0.f), fmaxf(d[1], 0.f));
                P.u[1] = pk2(fmaxf(d[2], 0.f), fmaxf(d[3], 0.f));
                P.u[2] = 0u; P.u[3] = 0u;
                f32x4 h = __builtin_amdgcn_mfma_f32_16x16x32_bf16(A2.v, P.v, c2, 0, 0, 0);
                const bool m = (base + t * 16 + col) < bposw;   // column's point id
#pragma unroll
                for (int r = 0; r < 4; ++r) {
                    accA[r] = fmaxf(accA[r], m ? h[r] : 0.f);
                    accB[r] = fmaxf(accB[r], m ? 0.f : h[r]);
                }
            }
        }
    }

    // ---- wave reduce across the 16 columns ----
#pragma unroll
    for (int mk = 1; mk <= 8; mk <<= 1) {
#pragma unroll
        for (int r = 0; r < 4; ++r) {
            accA[r] = fmaxf(accA[r], __shfl_xor(accA[r], mk));
            accB[r] = fmaxf(accB[r], __shfl_xor(accB[r], mk));
        }
    }
    if (col == 0) {   // lanes 0,16,32,48 hold dims 4g..4g+3
        *reinterpret_cast<float4*>(&lv[wid][0][4 * g]) =
            make_float4(accA[0], accA[1], accA[2], accA[3]);
        *reinterpret_cast<float4*>(&lv[wid][1][4 * g]) =
            make_float4(accB[0], accB[1], accB[2], accB[3]);
    }
    if (lane == 0) {
        li[wid][0] = idA; li[wid][1] = idB;
        lbp[wid]   = (idA != idB) ? bposw : 0x7fffffff;
    }
    __syncthreads();

    // ---- block combine (<=2 segments per 4096-pt block) ----
    if (threadIdx.x < NH) {
        const int d   = threadIdx.x;
        const int ida = li[0][0];
        const int idb = li[WPB - 1][1];
        float mA = 0.f, mB = 0.f;
#pragma unroll
        for (int s = 0; s < WPB; ++s)
#pragma unroll
            for (int hh = 0; hh < 2; ++hh) {
                const float val = lv[s][hh][d];
                if (li[s][hh] == ida) mA = fmaxf(mA, val);
                else                  mB = fmaxf(mB, val);
            }
        pv[(blockIdx.x * 2 + 0) * NH + d] = mA;
        pv[(blockIdx.x * 2 + 1) * NH + d] = mB;
        if (d == 0) {
            pid[blockIdx.x * 2 + 0] = ida;
            pid[blockIdx.x * 2 + 1] = idb;
            int bp = 0x7fffffff;
#pragma unroll
            for (int s = 0; s < WPB; ++s) {
                if (li[s][0] != ida) bp = min(bp, (int)(blockIdx.x * PPB + s * PTW));
                else if (lbp[s] != 0x7fffffff) bp = min(bp, lbp[s]);
            }
            Rec r; r.idA = ida; r.idB = idb; r.bpos = bp;
            recs[blockIdx.x] = r;
        }
    }
}

// ---------------- stage 2: combine partials, compute gate ----------------
__global__ __launch_bounds__(1024) void stage2_kernel(
    const float* __restrict__ pv, const int* __restrict__ pid,
    const float* __restrict__ Wg, const float* __restrict__ bg,
    const float* __restrict__ gum, float* __restrict__ gate)
{
    __shared__ unsigned int sm[NB * NH];   // 1024 floats-as-bits (vals >= 0)
    const int tid = threadIdx.x;
    sm[tid] = 0u;
    __syncthreads();

    // NENT*16 floats = NENT*4 float4s
#pragma unroll
    for (int i = tid; i < NENT * 4; i += 1024) {
        const float4 v = reinterpret_cast<const float4*>(pv)[i];
        const int e  = i >> 2;
        const int d0 = (i & 3) * 4;
        const int id = pid[e];
        atomicMax(&sm[id * NH + d0 + 0], __float_as_uint(v.x));
        atomicMax(&sm[id * NH + d0 + 1], __float_as_uint(v.y));
        atomicMax(&sm[id * NH + d0 + 2], __float_as_uint(v.z));
        atomicMax(&sm[id * NH + d0 + 3], __float_as_uint(v.w));
    }
    __syncthreads();

    if (tid < NB) {
        float l0 = bg[0] + gum[tid * 2 + 0];
        float l1 = bg[1] + gum[tid * 2 + 1];
#pragma unroll
        for (int k = 0; k < NH; ++k) {
            const float s = __uint_as_float(sm[tid * NH + k]);
            l0 = fmaf(s, Wg[k * 2 + 0], l0);
            l1 = fmaf(s, Wg[k * 2 + 1], l1);
        }
        gate[tid] = 1.f / (1.f + expf(-(l1 - l0)));   // softmax[:,1], TAU=1
    }
}

// ---------------- B: scale via records (no batch reads) ----------------
__global__ __launch_bounds__(256) void scale_kernel(
    const float* __restrict__ refl,
    const Rec*   __restrict__ recs,
    const float* __restrict__ gate,
    float* __restrict__ out)
{
    const Rec rec = recs[blockIdx.x >> 2];     // 4 scale-blocks per A-block
    const float gA = gate[rec.idA];
    const float gB = gate[rec.idB];

    const int p0 = (blockIdx.x * 256 + threadIdx.x) * 4;
    const float4 rr = *reinterpret_cast<const float4*>(refl + p0);
    float4 o;
    o.x = ((p0 + 0) < rec.bpos ? gA : gB) * rr.x;
    o.y = ((p0 + 1) < rec.bpos ? gA : gB) * rr.y;
    o.z = ((p0 + 2) < rec.bpos ? gA : gB) * rr.z;
    o.w = ((p0 + 3) < rec.bpos ? gA : gB) * rr.w;
    *reinterpret_cast<float4*>(out + p0) = o;
}

extern "C" void kernel_launch(void* const* d_in, const int* in_sizes, int n_in,
                              void* d_out, int out_size, void* d_ws, size_t ws_size,
                              hipStream_t stream) {
    const float* pos   = (const float*)d_in[0];
    const float* refl  = (const float*)d_in[1];
    const int*   batch = (const int*)d_in[2];
    const float* gumb  = (const float*)d_in[3];
    const float* W1    = (const float*)d_in[4];
    const float* b1    = (const float*)d_in[5];
    const float* W2    = (const float*)d_in[6];
    const float* b2    = (const float*)d_in[7];
    const float* Wg    = (const float*)d_in[8];
    const float* bg    = (const float*)d_in[9];
    float* out = (float*)d_out;

    // ws layout: pv 128KB | pid 8KB | recs 12KB | gate 256B
    float* pv   = (float*)d_ws;
    int*   pid  = (int*)((char*)d_ws + 131072);
    Rec*   recs = (Rec*)((char*)d_ws + 139264);
    float* gate = (float*)((char*)d_ws + 151552);

    mlp_segmax_kernel<<<NBLK, 256, 0, stream>>>(pos, refl, batch,
                                                W1, b1, W2, b2, pv, pid, recs);
    stage2_kernel<<<1, 1024, 0, stream>>>(pv, pid, Wg, bg, gumb, gate);
    scale_kernel<<<N_PTS / 1024, 256, 0, stream>>>(refl, recs, gate, out);
}